// Round 17
// baseline (323.061 us; speedup 1.0000x reference)
//
#include <hip/hip_runtime.h>

#define TT 48
#define DD 32
#define HH 64
#define BB 16384
#define LOG2E 1.4426950408889634f

typedef __bf16 bf16x8 __attribute__((ext_vector_type(8)));
typedef float f32x4 __attribute__((ext_vector_type(4)));

#define MFMA(a, b, c) __builtin_amdgcn_mfma_f32_16x16x32_bf16(a, b, c, 0, 0, 0)
#define BC(v) __builtin_bit_cast(bf16x8, v)

static __device__ __forceinline__ float exp2_f(float v) {
#if __has_builtin(__builtin_amdgcn_exp2f)
  return __builtin_amdgcn_exp2f(v);
#else
  return exp2f(v);
#endif
}
static __device__ __forceinline__ unsigned short bfu(float f) {
  __bf16 b = (__bf16)f;
  return __builtin_bit_cast(unsigned short, b);
}
// pre-scaled domain (y = x*log2e): sigmoid(x) = rcp(1 + 2^-y)
static __device__ __forceinline__ float sigm2(float y) {
  return __builtin_amdgcn_rcpf(1.f + exp2_f(-y));
}
// pre-scaled domain (y = 2x*log2e): tanh(x) = 1 - 2*rcp(1 + 2^y)
static __device__ __forceinline__ float tanh2(float y) {
  return fmaf(-2.f, __builtin_amdgcn_rcpf(1.f + exp2_f(y)), 1.f);
}

// ------------------------------------------------------------------
// Row bijection: tile m = g*4+hq (g = gate), tile-row = qp*4+r.
//   hidx(hq,qp,r) = (hq>>1)*32 + qp*8 + (hq&1)*4 + r
// Lane (b,qp)'s D outputs == exactly its next-step B-fragment slots ->
// h NEVER leaves the lane: zero LDS / shuffle / barrier in the recurrence.
// ------------------------------------------------------------------

// Kernel 0: linearize W (bf16 hi only) into per-lane MFMA A-fragment order,
// pre-scaled into the exp2 domain: i/f/o rows (and bias) * log2e, g rows * 2*log2e.
__global__ void prep_kernel(const float* __restrict__ W_ih, const float* __restrict__ W_hh,
                            const float* __restrict__ b_ih, const float* __restrict__ b_hh,
                            unsigned short* __restrict__ WhhL, unsigned short* __restrict__ WihL,
                            float* __restrict__ bsumL) {
  const int tid = threadIdx.x;  // 256 threads, 1 block
  const int l = tid & 63, qt = tid >> 6;
  const int rowl = l & 15, kq = (l >> 4) * 8;
  for (int mm = 0; mm < 4; ++mm) {
    const int m = qt * 4 + mm;
    const int g = m >> 2, hq = m & 3;
    const float s = (g == 2) ? 2.f * LOG2E : LOG2E;
    const int hidx = (hq >> 1) * 32 + (rowl >> 2) * 8 + (hq & 1) * 4 + (rowl & 3);
    const int orig = g * 64 + hidx;
    for (int c = 0; c < 2; ++c)
      for (int j = 0; j < 8; ++j)
        WhhL[(m * 2 + c) * 512 + l * 8 + j] = bfu(W_hh[orig * 64 + c * 32 + kq + j] * s);
    for (int j = 0; j < 8; ++j)
      WihL[m * 512 + l * 8 + j] = bfu(W_ih[orig * 32 + kq + j] * s);
    if ((l >> 4) == 0) bsumL[m * 16 + rowl] = (b_ih[orig] + b_hh[orig]) * s;
  }
}

// One LSTM step for one stream. x-MFMA first in each chain (no h dep);
// xv is consumed then refilled in place with x[t+1]; bh updated in place;
// c carried in the 2*log2e domain.
static __device__ __forceinline__ void lstm_step(
    const int t, const float* __restrict__ xp, float* __restrict__ opq,
    const float* av, float* xv,
    const f32x4 (&whhHi)[16][2], const f32x4 (&wihR)[16], const f32x4 (&biasR)[16],
    f32x4 (&creg)[4], bf16x8 (&bh)[2]) {
  // xw fragment for this step
  bf16x8 bxw;
#pragma unroll
  for (int j = 0; j < 8; ++j) bxw[j] = (__bf16)(xv[j] * av[j]);
  // refill xv with x[t+1] (clamped; final load dead but harmless)
  const int tn = (t + 1 < TT) ? (t + 1) : (TT - 1);
  {
    const float* xnp = xp + (size_t)tn * DD;
    float4 x0 = *(const float4*)xnp, x1 = *(const float4*)(xnp + 4);
    xv[0] = x0.x; xv[1] = x0.y; xv[2] = x0.z; xv[3] = x0.w;
    xv[4] = x1.x; xv[5] = x1.y; xv[6] = x1.z; xv[7] = x1.w;
  }
  bf16x8 nbh0, nbh1;
#pragma unroll
  for (int hq = 0; hq < 4; ++hq) {
    f32x4 acc[4];
#pragma unroll
    for (int g = 0; g < 4; ++g) {
      const int m = g * 4 + hq;
      f32x4 A = MFMA(BC(wihR[m]), bxw, biasR[m]);  // x chunk FIRST (no h dep)
      A = MFMA(BC(whhHi[m][0]), bh[0], A);         // k 0..31
      A = MFMA(BC(whhHi[m][1]), bh[1], A);         // k 32..63
      acc[g] = A;
    }
    float hr[4];
#pragma unroll
    for (int r = 0; r < 4; ++r) {
      float ig = sigm2(acc[0][r]);
      float fg = sigm2(acc[1][r]);
      float gts = fmaf(-4.f * LOG2E,
                       __builtin_amdgcn_rcpf(1.f + exp2_f(acc[2][r])), 2.f * LOG2E);
      float og = sigm2(acc[3][r]);
      float cns = fmaf(fg, creg[hq][r], ig * gts);  // c' = 2*log2e*c
      creg[hq][r] = cns;
      hr[r] = og * tanh2(cns);
    }
    float4 hv;
    hv.x = hr[0]; hv.y = hr[1]; hv.z = hr[2]; hv.w = hr[3];
    *(float4*)(opq + (size_t)t * HH + (hq >> 1) * 32 + (hq & 1) * 4) = hv;
#pragma unroll
    for (int r = 0; r < 4; ++r) {
      if (hq < 2) nbh0[hq * 4 + r] = (__bf16)hr[r];
      else nbh1[(hq - 2) * 4 + r] = (__bf16)hr[r];
    }
  }
  bh[0] = nbh0;
  bh[1] = nbh1;
}

// Fused attention prologue for one stream: logits -> softmax -> av,
// then the t-invariant out0 broadcast is written here (NOT in the loop).
static __device__ __forceinline__ void attn_prologue(
    const float* __restrict__ xp, const float* __restrict__ W_att,
    float* __restrict__ o0, float* av) {
  float p[8];
#pragma unroll
  for (int j = 0; j < 8; ++j) p[j] = 0.f;
#pragma unroll 4
  for (int t = 0; t < TT; ++t) {
    const float w = W_att[2 * HH + t];
    float4 x0 = *(const float4*)(xp + t * DD);
    float4 x1 = *(const float4*)(xp + t * DD + 4);
    p[0] = fmaf(x0.x, w, p[0]); p[1] = fmaf(x0.y, w, p[1]);
    p[2] = fmaf(x0.z, w, p[2]); p[3] = fmaf(x0.w, w, p[3]);
    p[4] = fmaf(x1.x, w, p[4]); p[5] = fmaf(x1.y, w, p[5]);
    p[6] = fmaf(x1.z, w, p[6]); p[7] = fmaf(x1.w, w, p[7]);
  }
  // softmax over d = 32: lanes l, l^16, l^32, l^48 share a batch row
  float mx = fmaxf(fmaxf(fmaxf(p[0], p[1]), fmaxf(p[2], p[3])),
                   fmaxf(fmaxf(p[4], p[5]), fmaxf(p[6], p[7])));
  mx = fmaxf(mx, __shfl_xor(mx, 16));
  mx = fmaxf(mx, __shfl_xor(mx, 32));
  float s = 0.f;
#pragma unroll
  for (int j = 0; j < 8; ++j) {
    av[j] = exp2_f((p[j] - mx) * LOG2E);
    s += av[j];
  }
  s += __shfl_xor(s, 16);
  s += __shfl_xor(s, 32);
  float inv = __builtin_amdgcn_rcpf(s);
#pragma unroll
  for (int j = 0; j < 8; ++j) av[j] *= inv;
  float4 a0, a1;
  a0.x = av[0]; a0.y = av[1]; a0.z = av[2]; a0.w = av[3];
  a1.x = av[4]; a1.y = av[5]; a1.z = av[6]; a1.w = av[7];
#pragma unroll 4
  for (int t = 0; t < TT; ++t) {
    *(float4*)(o0 + t * DD) = a0;
    *(float4*)(o0 + t * DD + 4) = a1;
  }
}

// ------------------------------------------------------------------
// Kernel 1: DUAL-STREAM fused attention + lane-local LSTM, v2 (register-
// disciplined). 256 blocks x 128 thr = 512 waves; each wave carries two
// independent 16-row groups A/B interleaved A(t),B(t),A(t+1),B(t+1) so
// each stream's MFMAs fill the other's pointwise/trans latency.
// Weights as proven in r13-15: whhHi 128 VGPR ("+v"), wih+bias 128 AGPR
// ("+a"). out0 hoisted to prologue; single xv buffer + in-place bh per
// stream. Target VGPR ~250 (r16's spill-FETCH signature must vanish).
// ------------------------------------------------------------------
__global__ __launch_bounds__(128, 1) void lstm_kernel(
    const float* __restrict__ x, const float* __restrict__ h0, const float* __restrict__ c0,
    const float* __restrict__ W_att, const unsigned short* __restrict__ WhhL,
    const unsigned short* __restrict__ WihL, const float* __restrict__ bsumL,
    float* __restrict__ out0, float* __restrict__ out1) {
  const int tid = threadIdx.x;
  const int l = tid & 63;
  const int wid = tid >> 6;
  const int b = l & 15;
  const int qp = l >> 4;
  const int wv = blockIdx.x * 2 + wid;
  const int browA = wv * 32 + b;
  const int browB = browA + 16;

  // resident weights: hi -> VGPR (128); wih, bias -> AGPR (128)
  f32x4 whhHi[16][2], wihR[16], biasR[16];
#pragma unroll
  for (int m = 0; m < 16; ++m) {
#pragma unroll
    for (int c = 0; c < 2; ++c)
      whhHi[m][c] = *(const f32x4*)(WhhL + ((m * 2 + c) << 9) + l * 8);
    wihR[m] = *(const f32x4*)(WihL + (m << 9) + l * 8);
    biasR[m] = *(const f32x4*)(bsumL + m * 16 + qp * 4);
  }
#pragma unroll
  for (int m = 0; m < 16; ++m) {
#pragma unroll
    for (int c = 0; c < 2; ++c) asm volatile("" : "+v"(whhHi[m][c]));
    asm volatile("" : "+a"(wihR[m]));
    asm volatile("" : "+a"(biasR[m]));
  }

  const float* xpA = x + (size_t)browA * (TT * DD) + qp * 8;
  const float* xpB = x + (size_t)browB * (TT * DD) + qp * 8;

  // fused attention + hoisted out0 writes, per stream
  float avA[8], avB[8];
  attn_prologue(xpA, W_att, out0 + (size_t)browA * (TT * DD) + qp * 8, avA);
  attn_prologue(xpB, W_att, out0 + (size_t)browB * (TT * DD) + qp * 8, avB);

  // c state (2*log2e domain) per stream
  f32x4 cregA[4], cregB[4];
#pragma unroll
  for (int hq = 0; hq < 4; ++hq) {
    const int off = (hq >> 1) * 32 + qp * 8 + (hq & 1) * 4;
    f32x4 ca = *(const f32x4*)(c0 + (size_t)browA * HH + off);
    f32x4 cb = *(const f32x4*)(c0 + (size_t)browB * HH + off);
#pragma unroll
    for (int r = 0; r < 4; ++r) {
      ca[r] *= 2.f * LOG2E;
      cb[r] *= 2.f * LOG2E;
    }
    cregA[hq] = ca;
    cregB[hq] = cb;
  }

  // h state per stream (single set, in-place update)
  bf16x8 bhA[2], bhB[2];
#pragma unroll
  for (int c = 0; c < 2; ++c) {
    const float* hpA = h0 + (size_t)browA * HH + c * 32 + qp * 8;
    const float* hpB = h0 + (size_t)browB * HH + c * 32 + qp * 8;
    float4 a0 = *(const float4*)hpA, a1 = *(const float4*)(hpA + 4);
    float4 b0 = *(const float4*)hpB, b1 = *(const float4*)(hpB + 4);
    float va[8] = {a0.x, a0.y, a0.z, a0.w, a1.x, a1.y, a1.z, a1.w};
    float vb[8] = {b0.x, b0.y, b0.z, b0.w, b1.x, b1.y, b1.z, b1.w};
#pragma unroll
    for (int j = 0; j < 8; ++j) {
      bhA[c][j] = (__bf16)va[j];
      bhB[c][j] = (__bf16)vb[j];
    }
  }

  float* opqA = out1 + (size_t)browA * (TT * HH) + qp * 8;
  float* opqB = out1 + (size_t)browB * (TT * HH) + qp * 8;

  // x buffers per stream (t = 0)
  float xvA[8], xvB[8];
  {
    float4 a0 = *(const float4*)xpA, a1 = *(const float4*)(xpA + 4);
    xvA[0] = a0.x; xvA[1] = a0.y; xvA[2] = a0.z; xvA[3] = a0.w;
    xvA[4] = a1.x; xvA[5] = a1.y; xvA[6] = a1.z; xvA[7] = a1.w;
    float4 b0 = *(const float4*)xpB, b1 = *(const float4*)(xpB + 4);
    xvB[0] = b0.x; xvB[1] = b0.y; xvB[2] = b0.z; xvB[3] = b0.w;
    xvB[4] = b1.x; xvB[5] = b1.y; xvB[6] = b1.z; xvB[7] = b1.w;
  }

#pragma unroll 1
  for (int t = 0; t < TT; t += 2) {
    lstm_step(t, xpA, opqA, avA, xvA, whhHi, wihR, biasR, cregA, bhA);
    lstm_step(t, xpB, opqB, avB, xvB, whhHi, wihR, biasR, cregB, bhB);
    lstm_step(t + 1, xpA, opqA, avA, xvA, whhHi, wihR, biasR, cregA, bhA);
    lstm_step(t + 1, xpB, opqB, avB, xvB, whhHi, wihR, biasR, cregB, bhB);
  }
}

extern "C" void kernel_launch(void* const* d_in, const int* in_sizes, int n_in,
                              void* d_out, int out_size, void* d_ws, size_t ws_size,
                              hipStream_t stream) {
  const float* x = (const float*)d_in[0];
  const float* h0 = (const float*)d_in[1];
  const float* c0 = (const float*)d_in[2];
  const float* W_att = (const float*)d_in[3];
  // d_in[4] = b_att: uniform shift, softmax-invariant -> unused
  const float* W_ih = (const float*)d_in[5];
  const float* W_hh = (const float*)d_in[6];
  const float* b_ih = (const float*)d_in[7];
  const float* b_hh = (const float*)d_in[8];

  float* out0 = (float*)d_out;                // attention [B,T,D]
  float* out1 = out0 + (size_t)BB * TT * DD;  // input_encoded [B,T,H]

  char* ws = (char*)d_ws;
  unsigned short* WhhL = (unsigned short*)ws;            // 32768 B (hi only)
  unsigned short* WihL = (unsigned short*)(ws + 32768);  // 16384 B
  float* bsumL = (float*)(ws + 49152);                   // 1024 B

  prep_kernel<<<1, 256, 0, stream>>>(W_ih, W_hh, b_ih, b_hh, WhhL, WihL, bsumL);
  lstm_kernel<<<BB / 64, 128, 0, stream>>>(x, h0, c0, W_att, WhhL, WihL, bsumL, out0, out1);
}

// Round 18
// 183.084 us; speedup vs baseline: 1.7646x; 1.7646x over previous
//
#include <hip/hip_runtime.h>

#define TT 48
#define DD 32
#define HH 64
#define BB 16384
#define LOG2E 1.4426950408889634f

typedef __bf16 bf16x8 __attribute__((ext_vector_type(8)));
typedef float f32x4 __attribute__((ext_vector_type(4)));

#define MFMA(a, b, c) __builtin_amdgcn_mfma_f32_16x16x32_bf16(a, b, c, 0, 0, 0)
#define BC(v) __builtin_bit_cast(bf16x8, v)

static __device__ __forceinline__ float exp2_f(float v) {
#if __has_builtin(__builtin_amdgcn_exp2f)
  return __builtin_amdgcn_exp2f(v);
#else
  return exp2f(v);
#endif
}
static __device__ __forceinline__ unsigned short bfu(float f) {
  __bf16 b = (__bf16)f;
  return __builtin_bit_cast(unsigned short, b);
}
// pre-scaled domain (y = x*log2e): sigmoid(x) = rcp(1 + 2^-y)
static __device__ __forceinline__ float sigm2(float y) {
  return __builtin_amdgcn_rcpf(1.f + exp2_f(-y));
}
// pre-scaled domain (y = 2x*log2e): tanh(x) = 1 - 2*rcp(1 + 2^y)
static __device__ __forceinline__ float tanh2(float y) {
  return fmaf(-2.f, __builtin_amdgcn_rcpf(1.f + exp2_f(y)), 1.f);
}

// ------------------------------------------------------------------
// Row bijection (pair form): wave `half` owns m-tiles m = g*4 + 2*half + e,
// producing h rows hidx = half*32 + qp*8 + e*4 + r — exactly its own
// next-step B-frag slots [half*32 + qp*8 .. +8). The other 32-chunk comes
// from the partner wave via a 16B/lane double-buffered LDS exchange with a
// RAW s_barrier (lgkmcnt-only wait: out1 HBM stores are NOT drained, unlike
// __syncthreads, which was the r10/r11 per-step ~600-900 cyc killer).
// ------------------------------------------------------------------

// Kernel 0: linearize W (bf16 hi only) into per-lane MFMA A-fragment order,
// pre-scaled into the exp2 domain: i/f/o rows (and bias) * log2e, g rows * 2*log2e.
__global__ void prep_kernel(const float* __restrict__ W_ih, const float* __restrict__ W_hh,
                            const float* __restrict__ b_ih, const float* __restrict__ b_hh,
                            unsigned short* __restrict__ WhhL, unsigned short* __restrict__ WihL,
                            float* __restrict__ bsumL) {
  const int tid = threadIdx.x;  // 256 threads, 1 block
  const int l = tid & 63, qt = tid >> 6;
  const int rowl = l & 15, kq = (l >> 4) * 8;
  for (int mm = 0; mm < 4; ++mm) {
    const int m = qt * 4 + mm;
    const int g = m >> 2, hq = m & 3;
    const float s = (g == 2) ? 2.f * LOG2E : LOG2E;
    const int hidx = (hq >> 1) * 32 + (rowl >> 2) * 8 + (hq & 1) * 4 + (rowl & 3);
    const int orig = g * 64 + hidx;
    for (int c = 0; c < 2; ++c)
      for (int j = 0; j < 8; ++j)
        WhhL[(m * 2 + c) * 512 + l * 8 + j] = bfu(W_hh[orig * 64 + c * 32 + kq + j] * s);
    for (int j = 0; j < 8; ++j)
      WihL[m * 512 + l * 8 + j] = bfu(W_ih[orig * 32 + kq + j] * s);
    if ((l >> 4) == 0) bsumL[m * 16 + rowl] = (b_ih[orig] + b_hh[orig]) * s;
  }
}

// ------------------------------------------------------------------
// Kernel 1: PAIR-SPLIT fused attention + LSTM with drain-free barriers.
// 1024 blocks x 128 thr = 2048 waves = 8 waves/CU (2/SIMD, gremlin-safe).
// Block = one pair covering 16 batch rows; wave `half` computes gates for
// h-chunk [half*32, +32): 8 m-tiles, 24 MFMAs/step, 8 pointwise elems/lane.
// Two waves per SIMD cover each other's dependency stalls (fine-grained
// interleave) — enabled by the raw-barrier (no vmcnt drain) exchange.
// whhO/whhX hi-only in 64 VGPR ("+v"); wih+bias in 64 AGPR ("+a").
// ------------------------------------------------------------------
__global__ __launch_bounds__(128, 2) void lstm_kernel(
    const float* __restrict__ x, const float* __restrict__ h0, const float* __restrict__ c0,
    const float* __restrict__ W_att, const unsigned short* __restrict__ WhhL,
    const unsigned short* __restrict__ WihL, const float* __restrict__ bsumL,
    float* __restrict__ out0, float* __restrict__ out1) {
  __shared__ __align__(16) char xch[4096];  // [buf][half][lane]*16B
  const int tid = threadIdx.x;
  const int l = tid & 63;
  const int half = tid >> 6;
  const int b = l & 15;
  const int qp = l >> 4;
  const int brow = blockIdx.x * 16 + b;

#define XOFF(buf, hf) (((buf) * 2 + (hf)) * 1024)

  // own-half weights: m = g*4 + 2*half + e. whhO contracts own chunk
  // (k-chunk c = half); whhX the partner chunk (c = 1^half).
  f32x4 whhO[2][4], whhX[2][4], wihR[2][4], biasR[2][4];
#pragma unroll
  for (int e = 0; e < 2; ++e)
#pragma unroll
    for (int g = 0; g < 4; ++g) {
      const int m = g * 4 + 2 * half + e;
      whhO[e][g] = *(const f32x4*)(WhhL + ((m * 2 + half) << 9) + l * 8);
      whhX[e][g] = *(const f32x4*)(WhhL + ((m * 2 + (1 ^ half)) << 9) + l * 8);
      wihR[e][g] = *(const f32x4*)(WihL + (m << 9) + l * 8);
      biasR[e][g] = *(const f32x4*)(bsumL + m * 16 + qp * 4);
    }
#pragma unroll
  for (int e = 0; e < 2; ++e)
#pragma unroll
    for (int g = 0; g < 4; ++g) {
      asm volatile("" : "+v"(whhO[e][g]));
      asm volatile("" : "+v"(whhX[e][g]));
      asm volatile("" : "+a"(wihR[e][g]));
      asm volatile("" : "+a"(biasR[e][g]));
    }

  const float* xp = x + (size_t)brow * (TT * DD) + qp * 8;

  // ---- fused attention (both waves compute av; only wave 0 stores out0) ----
  float av[8];
  {
    float p[8];
#pragma unroll
    for (int j = 0; j < 8; ++j) p[j] = 0.f;
#pragma unroll 4
    for (int t = 0; t < TT; ++t) {
      const float w = W_att[2 * HH + t];
      float4 x0 = *(const float4*)(xp + t * DD);
      float4 x1 = *(const float4*)(xp + t * DD + 4);
      p[0] = fmaf(x0.x, w, p[0]); p[1] = fmaf(x0.y, w, p[1]);
      p[2] = fmaf(x0.z, w, p[2]); p[3] = fmaf(x0.w, w, p[3]);
      p[4] = fmaf(x1.x, w, p[4]); p[5] = fmaf(x1.y, w, p[5]);
      p[6] = fmaf(x1.z, w, p[6]); p[7] = fmaf(x1.w, w, p[7]);
    }
    // softmax over d = 32: lanes l, l^16, l^32, l^48 share a batch row
    float mx = fmaxf(fmaxf(fmaxf(p[0], p[1]), fmaxf(p[2], p[3])),
                     fmaxf(fmaxf(p[4], p[5]), fmaxf(p[6], p[7])));
    mx = fmaxf(mx, __shfl_xor(mx, 16));
    mx = fmaxf(mx, __shfl_xor(mx, 32));
    float s = 0.f;
#pragma unroll
    for (int j = 0; j < 8; ++j) {
      av[j] = exp2_f((p[j] - mx) * LOG2E);
      s += av[j];
    }
    s += __shfl_xor(s, 16);
    s += __shfl_xor(s, 32);
    float inv = __builtin_amdgcn_rcpf(s);
#pragma unroll
    for (int j = 0; j < 8; ++j) av[j] *= inv;
    if (half == 0) {
      float4 a0, a1;
      a0.x = av[0]; a0.y = av[1]; a0.z = av[2]; a0.w = av[3];
      a1.x = av[4]; a1.y = av[5]; a1.z = av[6]; a1.w = av[7];
      float* o0 = out0 + (size_t)brow * (TT * DD) + qp * 8;
#pragma unroll 4
      for (int t = 0; t < TT; ++t) {
        *(float4*)(o0 + t * DD) = a0;
        *(float4*)(o0 + t * DD + 4) = a1;
      }
    }
  }

  // c state (2*log2e domain): creg[e][r] = 2log2e * c[brow][half*32+qp*8+e*4+r]
  f32x4 creg[2];
#pragma unroll
  for (int e = 0; e < 2; ++e) {
    f32x4 cv = *(const f32x4*)(c0 + (size_t)brow * HH + half * 32 + qp * 8 + e * 4);
#pragma unroll
    for (int r = 0; r < 4; ++r) cv[r] *= 2.f * LOG2E;
    creg[e] = cv;
  }

  // own h chunk (single bf16) + publish to exchange buf 0
  bf16x8 own;
  {
    const float* hp = h0 + (size_t)brow * HH + half * 32 + qp * 8;
    float4 v0 = *(const float4*)hp, v1 = *(const float4*)(hp + 4);
    float vv[8] = {v0.x, v0.y, v0.z, v0.w, v1.x, v1.y, v1.z, v1.w};
#pragma unroll
    for (int j = 0; j < 8; ++j) own[j] = (__bf16)vv[j];
    *(f32x4*)(xch + XOFF(0, half) + l * 16) = __builtin_bit_cast(f32x4, own);
  }

  float* op = out1 + (size_t)brow * (TT * HH) + half * 32 + qp * 8;
  float xv[8];
  {
    float4 x0 = *(const float4*)xp, x1 = *(const float4*)(xp + 4);
    xv[0] = x0.x; xv[1] = x0.y; xv[2] = x0.z; xv[3] = x0.w;
    xv[4] = x1.x; xv[5] = x1.y; xv[6] = x1.z; xv[7] = x1.w;
  }
  __syncthreads();  // once, before the loop (full drain OK here)

#pragma unroll 1
  for (int t = 0; t < TT; ++t) {
    const int cur = t & 1, nxt = cur ^ 1;
    // partner's h chunk from the current exchange buffer
    bf16x8 oth = BC(*(const f32x4*)(xch + XOFF(cur, 1 ^ half) + l * 16));
    // xw fragment for this step
    bf16x8 bxw;
#pragma unroll
    for (int j = 0; j < 8; ++j) bxw[j] = (__bf16)(xv[j] * av[j]);
    // refill xv with x[t+1] (clamped; final load dead but harmless)
    const int tn = (t + 1 < TT) ? (t + 1) : (TT - 1);
    {
      const float* xnp = xp + (size_t)tn * DD;
      float4 x0 = *(const float4*)xnp, x1 = *(const float4*)(xnp + 4);
      xv[0] = x0.x; xv[1] = x0.y; xv[2] = x0.z; xv[3] = x0.w;
      xv[4] = x1.x; xv[5] = x1.y; xv[6] = x1.z; xv[7] = x1.w;
    }

    bf16x8 ownNew;
#pragma unroll
    for (int e = 0; e < 2; ++e) {
      f32x4 acc[4];
#pragma unroll
      for (int g = 0; g < 4; ++g) {
        f32x4 A = MFMA(BC(wihR[e][g]), bxw, biasR[e][g]);  // x chunk FIRST
        A = MFMA(BC(whhO[e][g]), own, A);                  // own 32-chunk
        A = MFMA(BC(whhX[e][g]), oth, A);                  // partner chunk
        acc[g] = A;
      }
      float hr[4];
#pragma unroll
      for (int r = 0; r < 4; ++r) {
        float ig = sigm2(acc[0][r]);
        float fg = sigm2(acc[1][r]);
        float gts = fmaf(-4.f * LOG2E,
                         __builtin_amdgcn_rcpf(1.f + exp2_f(acc[2][r])), 2.f * LOG2E);
        float og = sigm2(acc[3][r]);
        float cns = fmaf(fg, creg[e][r], ig * gts);  // c' = 2*log2e*c
        creg[e][r] = cns;
        hr[r] = og * tanh2(cns);
      }
      float4 hv;
      hv.x = hr[0]; hv.y = hr[1]; hv.z = hr[2]; hv.w = hr[3];
      *(float4*)(op + (size_t)t * HH + e * 4) = hv;  // fire-and-forget HBM store
#pragma unroll
      for (int r = 0; r < 4; ++r) ownNew[e * 4 + r] = (__bf16)hr[r];
    }
    own = ownNew;
    // publish own new chunk, then DRAIN-FREE barrier: LDS-ordered only —
    // the out1 vmcnt stores stay in flight (unlike __syncthreads).
    *(f32x4*)(xch + XOFF(nxt, half) + l * 16) = __builtin_bit_cast(f32x4, own);
    asm volatile("s_waitcnt lgkmcnt(0)" ::: "memory");
    __builtin_amdgcn_sched_barrier(0);
    __builtin_amdgcn_s_barrier();
    __builtin_amdgcn_sched_barrier(0);
  }
#undef XOFF
}

extern "C" void kernel_launch(void* const* d_in, const int* in_sizes, int n_in,
                              void* d_out, int out_size, void* d_ws, size_t ws_size,
                              hipStream_t stream) {
  const float* x = (const float*)d_in[0];
  const float* h0 = (const float*)d_in[1];
  const float* c0 = (const float*)d_in[2];
  const float* W_att = (const float*)d_in[3];
  // d_in[4] = b_att: uniform shift, softmax-invariant -> unused
  const float* W_ih = (const float*)d_in[5];
  const float* W_hh = (const float*)d_in[6];
  const float* b_ih = (const float*)d_in[7];
  const float* b_hh = (const float*)d_in[8];

  float* out0 = (float*)d_out;                // attention [B,T,D]
  float* out1 = out0 + (size_t)BB * TT * DD;  // input_encoded [B,T,H]

  char* ws = (char*)d_ws;
  unsigned short* WhhL = (unsigned short*)ws;            // 32768 B (hi only)
  unsigned short* WihL = (unsigned short*)(ws + 32768);  // 16384 B
  float* bsumL = (float*)(ws + 49152);                   // 1024 B

  prep_kernel<<<1, 256, 0, stream>>>(W_ih, W_hh, b_ih, b_hh, WhhL, WihL, bsumL);
  lstm_kernel<<<BB / 16, 128, 0, stream>>>(x, h0, c0, W_att, WhhL, WihL, bsumL, out0, out1);
}

// Round 19
// 168.398 us; speedup vs baseline: 1.9184x; 1.0872x over previous
//
#include <hip/hip_runtime.h>

#define TT 48
#define DD 32
#define HH 64
#define BB 16384
#define LOG2E 1.4426950408889634f

typedef __bf16 bf16x8 __attribute__((ext_vector_type(8)));
typedef float f32x4 __attribute__((ext_vector_type(4)));

#define MFMA(a, b, c) __builtin_amdgcn_mfma_f32_16x16x32_bf16(a, b, c, 0, 0, 0)
#define BC(v) __builtin_bit_cast(bf16x8, v)

static __device__ __forceinline__ float exp2_f(float v) {
#if __has_builtin(__builtin_amdgcn_exp2f)
  return __builtin_amdgcn_exp2f(v);
#else
  return exp2f(v);
#endif
}
static __device__ __forceinline__ unsigned short bfu(float f) {
  __bf16 b = (__bf16)f;
  return __builtin_bit_cast(unsigned short, b);
}
// pre-scaled domain (y = x*log2e): sigmoid(x) = rcp(1 + 2^-y)
static __device__ __forceinline__ float sigm2(float y) {
  return __builtin_amdgcn_rcpf(1.f + exp2_f(-y));
}
// pre-scaled domain (y = 2x*log2e): tanh(x) = 1 - 2*rcp(1 + 2^y)
static __device__ __forceinline__ float tanh2(float y) {
  return fmaf(-2.f, __builtin_amdgcn_rcpf(1.f + exp2_f(y)), 1.f);
}

// ------------------------------------------------------------------
// Row bijection: tile m = g*4+hq (g = gate), tile-row = qp*4+r.
//   hidx(hq,qp,r) = (hq>>1)*32 + qp*8 + (hq&1)*4 + r
// Lane (b,qp)'s D outputs == exactly its next-step B-fragment slots ->
// h NEVER leaves the lane: zero LDS / shuffle / barrier in the recurrence.
// ------------------------------------------------------------------

// Kernel 0: linearize W (bf16 hi only) into per-lane MFMA A-fragment order,
// pre-scaled into the exp2 domain: i/f/o rows (and bias) * log2e, g rows * 2*log2e.
__global__ void prep_kernel(const float* __restrict__ W_ih, const float* __restrict__ W_hh,
                            const float* __restrict__ b_ih, const float* __restrict__ b_hh,
                            unsigned short* __restrict__ WhhL, unsigned short* __restrict__ WihL,
                            float* __restrict__ bsumL) {
  const int tid = threadIdx.x;  // 256 threads, 1 block
  const int l = tid & 63, qt = tid >> 6;
  const int rowl = l & 15, kq = (l >> 4) * 8;
  for (int mm = 0; mm < 4; ++mm) {
    const int m = qt * 4 + mm;
    const int g = m >> 2, hq = m & 3;
    const float s = (g == 2) ? 2.f * LOG2E : LOG2E;
    const int hidx = (hq >> 1) * 32 + (rowl >> 2) * 8 + (hq & 1) * 4 + (rowl & 3);
    const int orig = g * 64 + hidx;
    for (int c = 0; c < 2; ++c)
      for (int j = 0; j < 8; ++j)
        WhhL[(m * 2 + c) * 512 + l * 8 + j] = bfu(W_hh[orig * 64 + c * 32 + kq + j] * s);
    for (int j = 0; j < 8; ++j)
      WihL[m * 512 + l * 8 + j] = bfu(W_ih[orig * 32 + kq + j] * s);
    if ((l >> 4) == 0) bsumL[m * 16 + rowl] = (b_ih[orig] + b_hh[orig]) * s;
  }
}

// One LSTM step. x-MFMA is FIRST in each accumulation chain (no h
// dependency -> hoistable into the previous step's pointwise phase).
// xv is consumed for bxw, then reused as the prefetch buffer for t+2.
// c is carried in the 2*log2e domain (saves one mul per element).
static __device__ __forceinline__ void lstm_step(
    const int t, const float* __restrict__ xp,
    float* __restrict__ opq, const float* av, float* xv,
    const f32x4 (&whhHi)[16][2], const f32x4 (&wihR)[16], const f32x4 (&biasR)[16],
    f32x4 (&creg)[4], bf16x8 (&bhIn)[2], bf16x8 (&bhOut)[2]) {
  // xw fragment for this step
  bf16x8 bxw;
#pragma unroll
  for (int j = 0; j < 8; ++j) bxw[j] = (__bf16)(xv[j] * av[j]);
  // prefetch x[t+2] into the freed buffer (clamped; dead at the tail)
  const int tn = (t + 2 < TT) ? (t + 2) : (TT - 1);
  {
    const float* xnp = xp + (size_t)tn * DD;
    float4 x0 = *(const float4*)xnp, x1 = *(const float4*)(xnp + 4);
    xv[0] = x0.x; xv[1] = x0.y; xv[2] = x0.z; xv[3] = x0.w;
    xv[4] = x1.x; xv[5] = x1.y; xv[6] = x1.z; xv[7] = x1.w;
  }
#pragma unroll
  for (int hq = 0; hq < 4; ++hq) {
    f32x4 acc[4];
#pragma unroll
    for (int g = 0; g < 4; ++g) {
      const int m = g * 4 + hq;
      f32x4 A = MFMA(BC(wihR[m]), bxw, biasR[m]);  // x chunk FIRST (no h dep)
      A = MFMA(BC(whhHi[m][0]), bhIn[0], A);       // k 0..31
      A = MFMA(BC(whhHi[m][1]), bhIn[1], A);       // k 32..63
      acc[g] = A;
    }
    // pointwise: i/f/g/o lane-local (rows qp*4+r of tiles g*4+hq)
    float hr[4];
#pragma unroll
    for (int r = 0; r < 4; ++r) {
      float ig = sigm2(acc[0][r]);
      float fg = sigm2(acc[1][r]);
      // gt' = 2*log2e*tanh(g) (g rows pre-scaled by 2*log2e)
      float gts = fmaf(-4.f * LOG2E,
                       __builtin_amdgcn_rcpf(1.f + exp2_f(acc[2][r])), 2.f * LOG2E);
      float og = sigm2(acc[3][r]);
      float cns = fmaf(fg, creg[hq][r], ig * gts);  // c' = 2*log2e*c
      creg[hq][r] = cns;
      hr[r] = og * tanh2(cns);
    }
    // out1: contiguous float4 at hidx base (4 qp-lanes cover the full row)
    float4 hv;
    hv.x = hr[0]; hv.y = hr[1]; hv.z = hr[2]; hv.w = hr[3];
    *(float4*)(opq + (size_t)t * HH + (hq >> 1) * 32 + (hq & 1) * 4) = hv;
    // repack into next step's B-fragment (lane-local, single bf16)
#pragma unroll
    for (int r = 0; r < 4; ++r) bhOut[hq >> 1][(hq & 1) * 4 + r] = (__bf16)hr[r];
  }
}

// ------------------------------------------------------------------
// Kernel 1: FUSED attention + lane-local LSTM (r15 champion structure).
// 256 blocks x 256 thr = 4 waves/CU (1/SIMD). Barrier-free, zero LDS,
// 48 MFMAs/step. W_hh bf16-hi in 128 VGPR ("+v"); wih+bias in 128 AGPR
// ("+a", direct MFMA A/C operands). Main loop manually unrolled 2x with
// register double-buffers (xvA/xvB, bhA/bhB). out0 (t-invariant) stores
// hoisted to the prologue — not in the dependency-critical loop.
// ------------------------------------------------------------------
__global__ __launch_bounds__(256, 1) void lstm_kernel(
    const float* __restrict__ x, const float* __restrict__ h0, const float* __restrict__ c0,
    const float* __restrict__ W_att, const unsigned short* __restrict__ WhhL,
    const unsigned short* __restrict__ WihL, const float* __restrict__ bsumL,
    float* __restrict__ out0, float* __restrict__ out1) {
  const int tid = threadIdx.x;
  const int l = tid & 63;
  const int wid = tid >> 6;
  const int b = l & 15;
  const int qp = l >> 4;
  const int brow = blockIdx.x * 64 + wid * 16 + b;

  // resident weights: hi -> VGPR; wih, bias -> AGPR
  f32x4 whhHi[16][2], wihR[16], biasR[16];
#pragma unroll
  for (int m = 0; m < 16; ++m) {
#pragma unroll
    for (int c = 0; c < 2; ++c)
      whhHi[m][c] = *(const f32x4*)(WhhL + ((m * 2 + c) << 9) + l * 8);
    wihR[m] = *(const f32x4*)(WihL + (m << 9) + l * 8);
    biasR[m] = *(const f32x4*)(bsumL + m * 16 + qp * 4);
  }
#pragma unroll
  for (int m = 0; m < 16; ++m) {
#pragma unroll
    for (int c = 0; c < 2; ++c) asm volatile("" : "+v"(whhHi[m][c]));
    asm volatile("" : "+a"(wihR[m]));
    asm volatile("" : "+a"(biasR[m]));
  }

  const float* xp = x + (size_t)brow * (TT * DD) + qp * 8;

  // ---- fused attention: logits for this lane's d-slots ----
  float p[8];
#pragma unroll
  for (int j = 0; j < 8; ++j) p[j] = 0.f;
#pragma unroll 4
  for (int t = 0; t < TT; ++t) {
    const float w = W_att[2 * HH + t];
    float4 x0 = *(const float4*)(xp + t * DD);
    float4 x1 = *(const float4*)(xp + t * DD + 4);
    p[0] = fmaf(x0.x, w, p[0]); p[1] = fmaf(x0.y, w, p[1]);
    p[2] = fmaf(x0.z, w, p[2]); p[3] = fmaf(x0.w, w, p[3]);
    p[4] = fmaf(x1.x, w, p[4]); p[5] = fmaf(x1.y, w, p[5]);
    p[6] = fmaf(x1.z, w, p[6]); p[7] = fmaf(x1.w, w, p[7]);
  }
  // softmax over d = 32: lanes l, l^16, l^32, l^48 share a batch row
  float av[8];
  {
    float mx = fmaxf(fmaxf(fmaxf(p[0], p[1]), fmaxf(p[2], p[3])),
                     fmaxf(fmaxf(p[4], p[5]), fmaxf(p[6], p[7])));
    mx = fmaxf(mx, __shfl_xor(mx, 16));
    mx = fmaxf(mx, __shfl_xor(mx, 32));
    float s = 0.f;
#pragma unroll
    for (int j = 0; j < 8; ++j) {
      av[j] = exp2_f((p[j] - mx) * LOG2E);
      s += av[j];
    }
    s += __shfl_xor(s, 16);
    s += __shfl_xor(s, 32);
    float inv = __builtin_amdgcn_rcpf(s);
#pragma unroll
    for (int j = 0; j < 8; ++j) av[j] *= inv;
  }
  // out0 broadcast over t — hoisted out of the recurrence loop
  {
    float4 a0, a1;
    a0.x = av[0]; a0.y = av[1]; a0.z = av[2]; a0.w = av[3];
    a1.x = av[4]; a1.y = av[5]; a1.z = av[6]; a1.w = av[7];
    float* o0 = out0 + (size_t)brow * (TT * DD) + qp * 8;
#pragma unroll 4
    for (int t = 0; t < TT; ++t) {
      *(float4*)(o0 + t * DD) = a0;
      *(float4*)(o0 + t * DD + 4) = a1;
    }
  }

  // c state in the 2*log2e domain: creg[hq][r] = 2*log2e * c[brow][hidx(hq,qp,r)]
  f32x4 creg[4];
#pragma unroll
  for (int hq = 0; hq < 4; ++hq) {
    f32x4 cv = *(const f32x4*)(c0 + (size_t)brow * HH + (hq >> 1) * 32 + qp * 8 + (hq & 1) * 4);
#pragma unroll
    for (int r = 0; r < 4; ++r) cv[r] *= 2.f * LOG2E;
    creg[hq] = cv;
  }

  // h state as single-bf16 B-fragments
  bf16x8 bhA[2], bhB[2];
#pragma unroll
  for (int c = 0; c < 2; ++c) {
    const float* hp = h0 + (size_t)brow * HH + c * 32 + qp * 8;
    float4 v0 = *(const float4*)hp, v1 = *(const float4*)(hp + 4);
    float vv[8] = {v0.x, v0.y, v0.z, v0.w, v1.x, v1.y, v1.z, v1.w};
#pragma unroll
    for (int j = 0; j < 8; ++j) bhA[c][j] = (__bf16)vv[j];
  }

  float* opq = out1 + (size_t)brow * (TT * HH) + qp * 8;
  float xvA[8], xvB[8];
  {
    float4 x0 = *(const float4*)xp, x1 = *(const float4*)(xp + 4);
    xvA[0] = x0.x; xvA[1] = x0.y; xvA[2] = x0.z; xvA[3] = x0.w;
    xvA[4] = x1.x; xvA[5] = x1.y; xvA[6] = x1.z; xvA[7] = x1.w;
    float4 y0 = *(const float4*)(xp + DD), y1 = *(const float4*)(xp + DD + 4);
    xvB[0] = y0.x; xvB[1] = y0.y; xvB[2] = y0.z; xvB[3] = y0.w;
    xvB[4] = y1.x; xvB[5] = y1.y; xvB[6] = y1.z; xvB[7] = y1.w;
  }

#pragma unroll 1
  for (int t = 0; t < TT; t += 2) {
    lstm_step(t, xp, opq, av, xvA, whhHi, wihR, biasR, creg, bhA, bhB);
    lstm_step(t + 1, xp, opq, av, xvB, whhHi, wihR, biasR, creg, bhB, bhA);
  }
}

extern "C" void kernel_launch(void* const* d_in, const int* in_sizes, int n_in,
                              void* d_out, int out_size, void* d_ws, size_t ws_size,
                              hipStream_t stream) {
  const float* x = (const float*)d_in[0];
  const float* h0 = (const float*)d_in[1];
  const float* c0 = (const float*)d_in[2];
  const float* W_att = (const float*)d_in[3];
  // d_in[4] = b_att: uniform shift, softmax-invariant -> unused
  const float* W_ih = (const float*)d_in[5];
  const float* W_hh = (const float*)d_in[6];
  const float* b_ih = (const float*)d_in[7];
  const float* b_hh = (const float*)d_in[8];

  float* out0 = (float*)d_out;                // attention [B,T,D]
  float* out1 = out0 + (size_t)BB * TT * DD;  // input_encoded [B,T,H]

  char* ws = (char*)d_ws;
  unsigned short* WhhL = (unsigned short*)ws;            // 32768 B (hi only)
  unsigned short* WihL = (unsigned short*)(ws + 32768);  // 16384 B
  float* bsumL = (float*)(ws + 49152);                   // 1024 B

  prep_kernel<<<1, 256, 0, stream>>>(W_ih, W_hh, b_ih, b_hh, WhhL, WihL, bsumL);
  lstm_kernel<<<BB / 64, 256, 0, stream>>>(x, h0, c0, W_att, WhhL, WihL, bsumL, out0, out1);
}

// Round 20
// 120.145 us; speedup vs baseline: 2.6889x; 1.4016x over previous
//
#include <hip/hip_runtime.h>

#define TT 48
#define DD 32
#define HH 64
#define BB 16384
#define LOG2E 1.4426950408889634f

typedef __bf16 bf16x8 __attribute__((ext_vector_type(8)));
typedef float f32x4 __attribute__((ext_vector_type(4)));

#define MFMA(a, b, c) __builtin_amdgcn_mfma_f32_16x16x32_bf16(a, b, c, 0, 0, 0)
#define BC(v) __builtin_bit_cast(bf16x8, v)

static __device__ __forceinline__ float exp2_f(float v) {
#if __has_builtin(__builtin_amdgcn_exp2f)
  return __builtin_amdgcn_exp2f(v);
#else
  return exp2f(v);
#endif
}
static __device__ __forceinline__ unsigned short bfu(float f) {
  __bf16 b = (__bf16)f;
  return __builtin_bit_cast(unsigned short, b);
}
// pre-scaled domain (y = x*log2e): sigmoid(x) = rcp(1 + 2^-y)
static __device__ __forceinline__ float sigm2(float y) {
  return __builtin_amdgcn_rcpf(1.f + exp2_f(-y));
}
// pre-scaled domain (y = 2x*log2e): tanh(x) = 1 - 2*rcp(1 + 2^y)
static __device__ __forceinline__ float tanh2(float y) {
  return fmaf(-2.f, __builtin_amdgcn_rcpf(1.f + exp2_f(y)), 1.f);
}

// ------------------------------------------------------------------
// Row bijection: tile m = g*4+hq (g = gate), tile-row = qp*4+r.
//   hidx(hq,qp,r) = (hq>>1)*32 + qp*8 + (hq&1)*4 + r
// Lane (b,qp)'s D outputs == exactly its next-step B-fragment slots ->
// h NEVER leaves the lane: zero LDS / shuffle / barrier in the recurrence.
//
// r19 lesson (do NOT "clean up"): the t-invariant out0 stores MUST stay
// inside the loop — they trickle out under MFMA/trans stalls. Hoisting
// them to a prologue burst queues 96 stores ahead of the loop's
// latency-critical x loads in the per-wave in-order vmcnt queue
// (120 -> 168 us measured regression).
// ------------------------------------------------------------------

// Kernel 0: linearize W (bf16 hi only) into per-lane MFMA A-fragment order,
// pre-scaled into the exp2 domain: i/f/o rows (and bias) * log2e, g rows * 2*log2e.
__global__ void prep_kernel(const float* __restrict__ W_ih, const float* __restrict__ W_hh,
                            const float* __restrict__ b_ih, const float* __restrict__ b_hh,
                            unsigned short* __restrict__ WhhL, unsigned short* __restrict__ WihL,
                            float* __restrict__ bsumL) {
  const int tid = threadIdx.x;  // 256 threads, 1 block
  const int l = tid & 63, qt = tid >> 6;
  const int rowl = l & 15, kq = (l >> 4) * 8;
  for (int mm = 0; mm < 4; ++mm) {
    const int m = qt * 4 + mm;
    const int g = m >> 2, hq = m & 3;
    const float s = (g == 2) ? 2.f * LOG2E : LOG2E;
    const int hidx = (hq >> 1) * 32 + (rowl >> 2) * 8 + (hq & 1) * 4 + (rowl & 3);
    const int orig = g * 64 + hidx;
    for (int c = 0; c < 2; ++c)
      for (int j = 0; j < 8; ++j)
        WhhL[(m * 2 + c) * 512 + l * 8 + j] = bfu(W_hh[orig * 64 + c * 32 + kq + j] * s);
    for (int j = 0; j < 8; ++j)
      WihL[m * 512 + l * 8 + j] = bfu(W_ih[orig * 32 + kq + j] * s);
    if ((l >> 4) == 0) bsumL[m * 16 + rowl] = (b_ih[orig] + b_hh[orig]) * s;
  }
}

// One LSTM step. x-MFMA is FIRST in each accumulation chain (no h
// dependency -> hoistable into the previous step's pointwise phase).
// xv is consumed for bxw, then reused as the prefetch buffer for t+2.
// c is carried in the 2*log2e domain (saves one mul per element).
static __device__ __forceinline__ void lstm_step(
    const int t, const float* __restrict__ xp, float* __restrict__ o0,
    float* __restrict__ opq, const float* av, float* xv,
    const f32x4 (&whhHi)[16][2], const f32x4 (&wihR)[16], const f32x4 (&biasR)[16],
    f32x4 (&creg)[4], bf16x8 (&bhIn)[2], bf16x8 (&bhOut)[2],
    const float4 av0, const float4 av1) {
  // out0 broadcast write (full 128B line covered by the 4 qp-lanes per row)
  *(float4*)(o0 + t * DD) = av0;
  *(float4*)(o0 + t * DD + 4) = av1;
  // xw fragment for this step
  bf16x8 bxw;
#pragma unroll
  for (int j = 0; j < 8; ++j) bxw[j] = (__bf16)(xv[j] * av[j]);
  // prefetch x[t+2] into the freed buffer (clamped; dead at the tail)
  const int tn = (t + 2 < TT) ? (t + 2) : (TT - 1);
  {
    const float* xnp = xp + (size_t)tn * DD;
    float4 x0 = *(const float4*)xnp, x1 = *(const float4*)(xnp + 4);
    xv[0] = x0.x; xv[1] = x0.y; xv[2] = x0.z; xv[3] = x0.w;
    xv[4] = x1.x; xv[5] = x1.y; xv[6] = x1.z; xv[7] = x1.w;
  }
#pragma unroll
  for (int hq = 0; hq < 4; ++hq) {
    f32x4 acc[4];
#pragma unroll
    for (int g = 0; g < 4; ++g) {
      const int m = g * 4 + hq;
      f32x4 A = MFMA(BC(wihR[m]), bxw, biasR[m]);  // x chunk FIRST (no h dep)
      A = MFMA(BC(whhHi[m][0]), bhIn[0], A);       // k 0..31
      A = MFMA(BC(whhHi[m][1]), bhIn[1], A);       // k 32..63
      acc[g] = A;
    }
    // pointwise: i/f/g/o lane-local (rows qp*4+r of tiles g*4+hq)
    float hr[4];
#pragma unroll
    for (int r = 0; r < 4; ++r) {
      float ig = sigm2(acc[0][r]);
      float fg = sigm2(acc[1][r]);
      // gt' = 2*log2e*tanh(g) (g rows pre-scaled by 2*log2e)
      float gts = fmaf(-4.f * LOG2E,
                       __builtin_amdgcn_rcpf(1.f + exp2_f(acc[2][r])), 2.f * LOG2E);
      float og = sigm2(acc[3][r]);
      float cns = fmaf(fg, creg[hq][r], ig * gts);  // c' = 2*log2e*c
      creg[hq][r] = cns;
      hr[r] = og * tanh2(cns);
    }
    // out1: contiguous float4 at hidx base (4 qp-lanes cover the full row)
    float4 hv;
    hv.x = hr[0]; hv.y = hr[1]; hv.z = hr[2]; hv.w = hr[3];
    *(float4*)(opq + (size_t)t * HH + (hq >> 1) * 32 + (hq & 1) * 4) = hv;
    // repack into next step's B-fragment (lane-local, single bf16)
#pragma unroll
    for (int r = 0; r < 4; ++r) bhOut[hq >> 1][(hq & 1) * 4 + r] = (__bf16)hr[r];
  }
}

// ------------------------------------------------------------------
// Kernel 1: FUSED attention + lane-local LSTM (r15 champion, exact).
// 256 blocks x 256 thr = 4 waves/CU (1/SIMD). Barrier-free, zero LDS,
// 48 MFMAs/step. W_hh bf16-hi in 128 VGPR ("+v"); wih+bias in 128 AGPR
// ("+a", direct MFMA A/C operands). Main loop manually unrolled 2x with
// register double-buffers (xvA/xvB, bhA/bhB); out0 stores in-loop.
// ------------------------------------------------------------------
__global__ __launch_bounds__(256, 1) void lstm_kernel(
    const float* __restrict__ x, const float* __restrict__ h0, const float* __restrict__ c0,
    const float* __restrict__ W_att, const unsigned short* __restrict__ WhhL,
    const unsigned short* __restrict__ WihL, const float* __restrict__ bsumL,
    float* __restrict__ out0, float* __restrict__ out1) {
  const int tid = threadIdx.x;
  const int l = tid & 63;
  const int wid = tid >> 6;
  const int b = l & 15;
  const int qp = l >> 4;
  const int brow = blockIdx.x * 64 + wid * 16 + b;

  // resident weights: hi -> VGPR; wih, bias -> AGPR
  f32x4 whhHi[16][2], wihR[16], biasR[16];
#pragma unroll
  for (int m = 0; m < 16; ++m) {
#pragma unroll
    for (int c = 0; c < 2; ++c)
      whhHi[m][c] = *(const f32x4*)(WhhL + ((m * 2 + c) << 9) + l * 8);
    wihR[m] = *(const f32x4*)(WihL + (m << 9) + l * 8);
    biasR[m] = *(const f32x4*)(bsumL + m * 16 + qp * 4);
  }
#pragma unroll
  for (int m = 0; m < 16; ++m) {
#pragma unroll
    for (int c = 0; c < 2; ++c) asm volatile("" : "+v"(whhHi[m][c]));
    asm volatile("" : "+a"(wihR[m]));
    asm volatile("" : "+a"(biasR[m]));
  }

  const float* xp = x + (size_t)brow * (TT * DD) + qp * 8;

  // ---- fused attention: logits for this lane's d-slots ----
  float p[8];
#pragma unroll
  for (int j = 0; j < 8; ++j) p[j] = 0.f;
#pragma unroll 4
  for (int t = 0; t < TT; ++t) {
    const float w = W_att[2 * HH + t];
    float4 x0 = *(const float4*)(xp + t * DD);
    float4 x1 = *(const float4*)(xp + t * DD + 4);
    p[0] = fmaf(x0.x, w, p[0]); p[1] = fmaf(x0.y, w, p[1]);
    p[2] = fmaf(x0.z, w, p[2]); p[3] = fmaf(x0.w, w, p[3]);
    p[4] = fmaf(x1.x, w, p[4]); p[5] = fmaf(x1.y, w, p[5]);
    p[6] = fmaf(x1.z, w, p[6]); p[7] = fmaf(x1.w, w, p[7]);
  }
  // softmax over d = 32: lanes l, l^16, l^32, l^48 share a batch row
  float av[8];
  {
    float mx = fmaxf(fmaxf(fmaxf(p[0], p[1]), fmaxf(p[2], p[3])),
                     fmaxf(fmaxf(p[4], p[5]), fmaxf(p[6], p[7])));
    mx = fmaxf(mx, __shfl_xor(mx, 16));
    mx = fmaxf(mx, __shfl_xor(mx, 32));
    float s = 0.f;
#pragma unroll
    for (int j = 0; j < 8; ++j) {
      av[j] = exp2_f((p[j] - mx) * LOG2E);
      s += av[j];
    }
    s += __shfl_xor(s, 16);
    s += __shfl_xor(s, 32);
    float inv = __builtin_amdgcn_rcpf(s);
#pragma unroll
    for (int j = 0; j < 8; ++j) av[j] *= inv;
  }
  float4 av0, av1;
  av0.x = av[0]; av0.y = av[1]; av0.z = av[2]; av0.w = av[3];
  av1.x = av[4]; av1.y = av[5]; av1.z = av[6]; av1.w = av[7];
  float* o0 = out0 + (size_t)brow * (TT * DD) + qp * 8;

  // c state in the 2*log2e domain: creg[hq][r] = 2*log2e * c[brow][hidx(hq,qp,r)]
  f32x4 creg[4];
#pragma unroll
  for (int hq = 0; hq < 4; ++hq) {
    f32x4 cv = *(const f32x4*)(c0 + (size_t)brow * HH + (hq >> 1) * 32 + qp * 8 + (hq & 1) * 4);
#pragma unroll
    for (int r = 0; r < 4; ++r) cv[r] *= 2.f * LOG2E;
    creg[hq] = cv;
  }

  // h state as single-bf16 B-fragments
  bf16x8 bhA[2], bhB[2];
#pragma unroll
  for (int c = 0; c < 2; ++c) {
    const float* hp = h0 + (size_t)brow * HH + c * 32 + qp * 8;
    float4 v0 = *(const float4*)hp, v1 = *(const float4*)(hp + 4);
    float vv[8] = {v0.x, v0.y, v0.z, v0.w, v1.x, v1.y, v1.z, v1.w};
#pragma unroll
    for (int j = 0; j < 8; ++j) bhA[c][j] = (__bf16)vv[j];
  }

  float* opq = out1 + (size_t)brow * (TT * HH) + qp * 8;
  float xvA[8], xvB[8];
  {
    float4 x0 = *(const float4*)xp, x1 = *(const float4*)(xp + 4);
    xvA[0] = x0.x; xvA[1] = x0.y; xvA[2] = x0.z; xvA[3] = x0.w;
    xvA[4] = x1.x; xvA[5] = x1.y; xvA[6] = x1.z; xvA[7] = x1.w;
    float4 y0 = *(const float4*)(xp + DD), y1 = *(const float4*)(xp + DD + 4);
    xvB[0] = y0.x; xvB[1] = y0.y; xvB[2] = y0.z; xvB[3] = y0.w;
    xvB[4] = y1.x; xvB[5] = y1.y; xvB[6] = y1.z; xvB[7] = y1.w;
  }

#pragma unroll 1
  for (int t = 0; t < TT; t += 2) {
    lstm_step(t, xp, o0, opq, av, xvA, whhHi, wihR, biasR, creg, bhA, bhB, av0, av1);
    lstm_step(t + 1, xp, o0, opq, av, xvB, whhHi, wihR, biasR, creg, bhB, bhA, av0, av1);
  }
}

extern "C" void kernel_launch(void* const* d_in, const int* in_sizes, int n_in,
                              void* d_out, int out_size, void* d_ws, size_t ws_size,
                              hipStream_t stream) {
  const float* x = (const float*)d_in[0];
  const float* h0 = (const float*)d_in[1];
  const float* c0 = (const float*)d_in[2];
  const float* W_att = (const float*)d_in[3];
  // d_in[4] = b_att: uniform shift, softmax-invariant -> unused
  const float* W_ih = (const float*)d_in[5];
  const float* W_hh = (const float*)d_in[6];
  const float* b_ih = (const float*)d_in[7];
  const float* b_hh = (const float*)d_in[8];

  float* out0 = (float*)d_out;                // attention [B,T,D]
  float* out1 = out0 + (size_t)BB * TT * DD;  // input_encoded [B,T,H]

  char* ws = (char*)d_ws;
  unsigned short* WhhL = (unsigned short*)ws;            // 32768 B (hi only)
  unsigned short* WihL = (unsigned short*)(ws + 32768);  // 16384 B
  float* bsumL = (float*)(ws + 49152);                   // 1024 B

  prep_kernel<<<1, 256, 0, stream>>>(W_ih, W_hh, b_ih, b_hh, WhhL, WihL, bsumL);
  lstm_kernel<<<BB / 64, 256, 0, stream>>>(x, h0, c0, W_att, WhhL, WihL, bsumL, out0, out1);
}